// Round 5
// baseline (1667.168 us; speedup 1.0000x reference)
//
#include <hip/hip_runtime.h>

typedef unsigned short u16;

#define NWG 256
#define NT  256
#define TS  512
#define HD  1024
#define BS  128
#define NI  64
#define NO  64
#define XR  16      // batch rows per XCD
#define CC  32      // hidden cols per CU
#define RCP 17      // redC padded row stride
#define MBW2 32     // u32 words per (consumer,wave) mailbox line (128B)

typedef __attribute__((ext_vector_type(8))) short bf16x8;
typedef __attribute__((ext_vector_type(4))) float f32x4;

__device__ __forceinline__ float bf2f(u16 u) {
    union { unsigned int i; float f; } v; v.i = ((unsigned int)u) << 16; return v.f;
}
__device__ __forceinline__ u16 f2bf(float f) {
    union { float fl; unsigned int i; } v; v.fl = f;
    unsigned int x = v.i;
    return (u16)((x + 0x7fffu + ((x >> 16) & 1u)) >> 16);  // RNE, finite inputs
}
__device__ __forceinline__ float ldv(const void* p, size_t i, bool isf32) {
    return isf32 ? ((const float*)p)[i] : bf2f(((const u16*)p)[i]);
}

// L2-executed atomic returning old value (sc0 = return-old).
// Round-3 lesson: flag POLLS must be atomics (plain sc0-load spin never
// observes peer stores -> hang). Round-1 lesson: plain-store publish +
// atomic poll bounces lines to HBM (+240MB writes). The ONLY proven
// transport is atomic publish + atomic poll.
__device__ __forceinline__ unsigned l2_atomic_add(unsigned* p, unsigned v) {
    unsigned old;
    asm volatile("global_atomic_add %0, %1, %2, off sc0\n\t"
                 "s_waitcnt vmcnt(0)"
                 : "=&v"(old) : "v"(p), "v"(v) : "memory");
    return old;
}
// Fire-and-forget atomic SWAP publish. Single writer per word => no RMW
// accumulation at the coherence point.
__device__ __forceinline__ void l2_atomic_swap_nr(unsigned* p, unsigned v) {
    asm volatile("global_atomic_swap %0, %1, off" :: "v"(p), "v"(v) : "memory");
}

// 8 A-fragments (one K-quarter) via sc0 loads (L1 bypass -> XCD L2, where peer
// CUs' write-through stores live). Proven correct for *data* across sessions.
__device__ __forceinline__ void load_a_frags(const u16* ap, bf16x8* a) {
    asm volatile(
        "global_load_dwordx4 %0, %8, off sc0\n\t"
        "global_load_dwordx4 %1, %8, off offset:64 sc0\n\t"
        "global_load_dwordx4 %2, %8, off offset:128 sc0\n\t"
        "global_load_dwordx4 %3, %8, off offset:192 sc0\n\t"
        "global_load_dwordx4 %4, %8, off offset:256 sc0\n\t"
        "global_load_dwordx4 %5, %8, off offset:320 sc0\n\t"
        "global_load_dwordx4 %6, %8, off offset:384 sc0\n\t"
        "global_load_dwordx4 %7, %8, off offset:448 sc0\n\t"
        "s_waitcnt vmcnt(0)"
        : "=&v"(a[0]), "=&v"(a[1]), "=&v"(a[2]), "=&v"(a[3]),
          "=&v"(a[4]), "=&v"(a[5]), "=&v"(a[6]), "=&v"(a[7])
        : "v"(ap) : "memory");
}

// PER-WAVE flags (this round -- removes barrier2 from the serial chain):
// mb[xcd][consumer(32)][cwave(4)][producer_cu(8)][pwave(4)] u32. Each
// (consumer,wave) owns a private 128B line of the 32 flags it depends on
// (its K-quarter's 8 producer CUs x 4 waves). Producer wave u of slot s
// publishes value v=t+2 (h_{t+1} stored+drained by THIS WAVE: rows 4u..4u+3,
// all 32 cols -- the er2 mapping makes wave u own exactly those rows) the
// moment its own vmcnt(0) ack lands. No cross-wave join on the producer side.
// Safety:
//  RAW: consumer wave w's poll set covers all 4 waves of its 8 producers.
//  WAR(h ping-pong): consumer's h_{t+1} stores are after barrier1, which
//   joins its 4 waves' polls; union = ALL 32x4 flags >= t+1, and flag t+1
//   from wave (q,u) implies (q,u) finished reading h_{t-1}.
//  WAR(redC): redC is ping-ponged by step parity; cross-step reuse is
//   covered transitively (flag t+2 from any CU => it passed barrier1(t)
//   => its waves' polls => all flags >= t+1 => everyone left step t-1).

// LDS ~113KB (>80KB) -> exactly 1 WG/CU (required by the ticket scheme).
__global__ __launch_bounds__(NT)
void arnn_xcd(const void* __restrict__ xv,
              const void* __restrict__ encwv,
              const void* __restrict__ encbv,
              const void* __restrict__ recwv,
              const void* __restrict__ fgtwv,
              const void* __restrict__ decwv,
              const void* __restrict__ decbv,
              const void* __restrict__ hinitwv,
              const void* __restrict__ hinitbv,
              void* __restrict__ outv,
              u16* __restrict__ h0buf,
              u16* __restrict__ h1buf,
              unsigned* __restrict__ tickets,
              unsigned* __restrict__ mboxes)
{
    // WB: TWO-PASS staging (pass1 rec+enc, pass2 fgt) -> half the old size,
    // freeing room for the redC ping-pong.
    __shared__ short WB[68 * 64 * 8];            // 69632 B
    __shared__ float redC[2][4 * 5 * 16 * RCP];  // 2 x 21760 B ping-pong
    __shared__ unsigned s_xcd, s_slot;
    __shared__ int s_f32;

    const int tid  = threadIdx.x;
    const int wave = tid >> 6;
    const int lane = tid & 63;
    const int m    = lane & 15;      // C row / A row (batch-local)
    const int quad = lane >> 4;      // k-subblock within K=32

    // ---- identify XCD, claim per-XCD CU slot ----
    if (tid == 0) {
        unsigned xcc;
        asm volatile("s_getreg_b32 %0, hwreg(HW_REG_XCC_ID, 0, 4)" : "=s"(xcc));
        xcc &= 7u;
        unsigned slot = l2_atomic_add(tickets + xcc * 16, 1u);
        s_xcd = xcc;
        s_slot = slot & 31u;
        s_f32 = 0;
    }
    __syncthreads();
    { // runtime dtype detection on rec_w raw bits
        float v = bf2f(((const u16*)recwv)[tid]);
        if (!(v >= -1.0f && v <= 1.0f)) s_f32 = 1;
    }
    __syncthreads();
    const bool isf32 = (s_f32 != 0);
    const int xcd  = (int)s_xcd;
    const int slot = (int)s_slot;
    const int b0   = xcd * XR;       // this XCD's batch rows
    const int j0   = slot * CC;      // this CU's hidden cols
    const int dt   = slot & 3;       // dec tile: out cols 16dt..16dt+15
    const int rg   = slot >> 2;      // dec row-group: rows 2rg..2rg+1
    unsigned* mbX = mboxes + (size_t)xcd * 32 * 4 * MBW2;   // XCD's flag block
    unsigned* mbW = mbX + (slot * 4 + wave) * MBW2;         // this wave's 32 flags
    const int pw = (slot >> 3), pi = (slot & 7);            // producer word coords

    // ---- stage weights: PASS 1 = rec tiles 0,1 + enc tails (68 ksg) ----
    for (int idx = tid; idx < 68 * 64; idx += NT) {
        int ksg = idx >> 6, l = idx & 63, n = l & 15, q = l >> 4;
        int tile = (ksg < 34) ? 0 : 1;
        int ksl  = ksg - 34 * tile;
        int j = j0 + (tile << 4) + n;
        bf16x8 v;
        if (!isf32) {
            const u16* src = (ksl < 32) ? (const u16*)recwv + (size_t)j * HD + ksl * 32 + q * 8
                                        : (const u16*)encwv + (size_t)j * NI + (ksl - 32) * 32 + q * 8;
            v = *(const bf16x8*)src;
        } else {
            const float* src = (ksl < 32) ? (const float*)recwv + (size_t)j * HD + ksl * 32 + q * 8
                                          : (const float*)encwv + (size_t)j * NI + (ksl - 32) * 32 + q * 8;
            #pragma unroll
            for (int i = 0; i < 8; ++i) v[i] = (short)f2bf(src[i]);
        }
        *(bf16x8*)&WB[idx * 8] = v;
    }
    __syncthreads();

    bf16x8 Breg[2][8];   // rec tiles 0,1 for this wave's K-quarter
    #pragma unroll
    for (int ks = 0; ks < 8; ++ks) {
        int kb = wave * 8 + ks;
        Breg[0][ks] = *(const bf16x8*)&WB[((0  + kb) * 64 + lane) * 8];
        Breg[1][ks] = *(const bf16x8*)&WB[((34 + kb) * 64 + lane) * 8];
    }
    bf16x8 Ereg[2];      // enc-tail B-frags (waves 0,1 only)
    if (wave < 2) {
        Ereg[0] = *(const bf16x8*)&WB[((32 + wave) * 64 + lane) * 8];
        Ereg[1] = *(const bf16x8*)&WB[((34 + 32 + wave) * 64 + lane) * 8];
    }
    __syncthreads();     // pass-1 pulls complete before WB overwrite

    // ---- PASS 2 = fgt tiles 2,3 (64 ksg) ----
    for (int idx = tid; idx < 64 * 64; idx += NT) {
        int ksg = idx >> 6, l = idx & 63, n = l & 15, q = l >> 4;
        int tile = ksg >> 5;          // 0,1 -> fgt tile
        int ksl  = ksg & 31;
        int j = j0 + (tile << 4) + n;
        bf16x8 v;
        if (!isf32) {
            v = *(const bf16x8*)((const u16*)fgtwv + (size_t)j * HD + ksl * 32 + q * 8);
        } else {
            const float* src = (const float*)fgtwv + (size_t)j * HD + ksl * 32 + q * 8;
            #pragma unroll
            for (int i = 0; i < 8; ++i) v[i] = (short)f2bf(src[i]);
        }
        *(bf16x8*)&WB[idx * 8] = v;
    }
    __syncthreads();

    bf16x8 Freg[2][8];   // fgt tiles 0,1 for this wave's K-quarter
    #pragma unroll
    for (int ks = 0; ks < 8; ++ks) {
        int kb = wave * 8 + ks;
        Freg[0][ks] = *(const bf16x8*)&WB[((0  + kb) * 64 + lane) * 8];
        Freg[1][ks] = *(const bf16x8*)&WB[((32 + kb) * 64 + lane) * 8];
    }

    bf16x8 dfr[8];       // dec B-frags for this wave's K-quarter (direct from global)
    {
        int o = 16 * dt + m;
        #pragma unroll
        for (int ks = 0; ks < 8; ++ks) {
            int kb = wave * 256 + ks * 32 + quad * 8;
            if (!isf32) dfr[ks] = *(const bf16x8*)((const u16*)decwv + (size_t)o * HD + kb);
            else {
                const float* src = (const float*)decwv + (size_t)o * HD + kb;
                #pragma unroll
                for (int i = 0; i < 8; ++i) dfr[ks][i] = (short)f2bf(src[i]);
            }
        }
    }
    // per-thread scalars; h state in registers. Thread owns (row er2, cols
    // ec2/ec2+1); wave u covers rows 4u..4u+3 (basis of per-wave flags).
    const int er2 = tid >> 4, ec2 = (tid & 15) * 2;
    float encb0 = ldv(encbv, j0 + ec2,     isf32);
    float encb1 = ldv(encbv, j0 + ec2 + 1, isf32);
    float decb_r = ldv(decbv, 16 * dt + (tid & 15), isf32);
    float hstA = ldv(hinitwv, j0 + ec2,     isf32) + ldv(hinitbv, j0 + ec2,     isf32);
    float hstB = ldv(hinitwv, j0 + ec2 + 1, isf32) + ldv(hinitbv, j0 + ec2 + 1, isf32);
    {
        unsigned pack = (unsigned)f2bf(hstA) | ((unsigned)f2bf(hstB) << 16);
        *(unsigned*)&h0buf[(size_t)(b0 + er2) * HD + j0 + ec2] = pack;
    }
    // per-wave drain + per-wave publish of h_0 (value 1)
    asm volatile("s_waitcnt vmcnt(0)" ::: "memory");
    if (lane < 32)
        l2_atomic_swap_nr(mbX + (lane * 4 + pw) * MBW2 + pi * 4 + wave, 1u);

    // x prefetch (one step ahead)
    bf16x8 xpB = {};
    f32x4 xr0 = {}, xr1 = {};
    if (wave < 2) {
        size_t xb = (size_t)(b0 + m) * (TS * NI) + 0 * NI + wave * 32 + quad * 8;
        if (!isf32) xpB = *(const bf16x8*)((const u16*)xv + xb);
        else { const float* xp = (const float*)xv + xb;
               xr0 = *(const f32x4*)xp; xr1 = *(const f32x4*)(xp + 4); }
    }

    // ---- recurrence: ONE barrier per step ----
    for (int t = 0; t < TS; ++t) {
        float* rc = redC[t & 1];     // ping-pong: this step's reduction buffer
        f32x4 acc[5];
        #pragma unroll
        for (int tt = 0; tt < 5; ++tt) acc[tt] = (f32x4){0.f, 0.f, 0.f, 0.f};

        // enc contribution BEFORE the wait (x prefetched last iteration)
        if (wave < 2) {
            bf16x8 xf;
            if (!isf32) xf = xpB;
            else {
                #pragma unroll
                for (int i = 0; i < 4; ++i) {
                    xf[i]     = (short)f2bf(xr0[i]);
                    xf[i + 4] = (short)f2bf(xr1[i]);
                }
            }
            acc[0] = __builtin_amdgcn_mfma_f32_16x16x32_bf16(xf, Ereg[0], acc[0], 0, 0, 0);
            acc[1] = __builtin_amdgcn_mfma_f32_16x16x32_bf16(xf, Ereg[1], acc[1], 0, 0, 0);
        }

        // Per-wave poll: one 32-lane atomic gather of this wave's OWN 32
        // producer-wave flags (private 128B line).
        {
            const unsigned target = (unsigned)(t + 1);
            for (;;) {
                unsigned v = target;
                if (lane < 32) v = l2_atomic_add(mbW + lane, 0u);
                if (__all((int)(v >= target))) break;
            }
        }

        const u16* cur = (t & 1) ? h1buf : h0buf;
        u16*       nxt = (t & 1) ? h0buf : h1buf;

        bf16x8 a[8];
        load_a_frags(cur + (size_t)(b0 + m) * HD + wave * 256 + quad * 8, a);

        // next step's x prefetch (completes during MFMA/elementwise; its
        // vmcnt is absorbed well before the pre-publish drain)
        if (wave < 2) {
            int tn = (t + 1 < TS) ? t + 1 : t;
            size_t xb = (size_t)(b0 + m) * (TS * NI) + (size_t)tn * NI + wave * 32 + quad * 8;
            if (!isf32) xpB = *(const bf16x8*)((const u16*)xv + xb);
            else { const float* xp = (const float*)xv + xb;
                   xr0 = *(const f32x4*)xp; xr1 = *(const f32x4*)(xp + 4); }
        }

        #pragma unroll
        for (int ks = 0; ks < 8; ++ks) {
            acc[0] = __builtin_amdgcn_mfma_f32_16x16x32_bf16(a[ks], Breg[0][ks], acc[0], 0, 0, 0);
            acc[1] = __builtin_amdgcn_mfma_f32_16x16x32_bf16(a[ks], Breg[1][ks], acc[1], 0, 0, 0);
            acc[2] = __builtin_amdgcn_mfma_f32_16x16x32_bf16(a[ks], Freg[0][ks], acc[2], 0, 0, 0);
            acc[3] = __builtin_amdgcn_mfma_f32_16x16x32_bf16(a[ks], Freg[1][ks], acc[3], 0, 0, 0);
            acc[4] = __builtin_amdgcn_mfma_f32_16x16x32_bf16(a[ks], dfr[ks],     acc[4], 0, 0, 0);
        }

        // C-layout 16x16: col = lane&15, row = quad*4 + reg
        #pragma unroll
        for (int tt = 0; tt < 5; ++tt) {
            #pragma unroll
            for (int r = 0; r < 4; ++r)
                rc[((wave * 5 + tt) * 16 + quad * 4 + r) * RCP + m] = acc[tt][r];
        }
        __syncthreads();             // barrier1: redC(t) complete; joins polls

        // elementwise: h_{t+1} for this thread's 2 cols; ONE packed dword store
        {
            const int tl = ec2 >> 4, c0 = ec2 & 15;
            float pr0 = encb0, pf0 = 0.f, pr1 = encb1, pf1 = 0.f;
            #pragma unroll
            for (int kq = 0; kq < 4; ++kq) {
                pr0 += rc[((kq * 5 + tl) * 16 + er2) * RCP + c0];
                pf0 += rc[((kq * 5 + 2 + tl) * 16 + er2) * RCP + c0];
                pr1 += rc[((kq * 5 + tl) * 16 + er2) * RCP + c0 + 1];
                pf1 += rc[((kq * 5 + 2 + tl) * 16 + er2) * RCP + c0 + 1];
            }
            float fg0 = 1.0f / (1.0f + __expf(-pf0));
            float hn0 = pr0 / (1.0f + fabsf(pr0));
            hstA = hstA + fg0 * (hn0 - hstA);
            float fg1 = 1.0f / (1.0f + __expf(-pf1));
            float hn1 = pr1 / (1.0f + fabsf(pr1));
            hstB = hstB + fg1 * (hn1 - hstB);
            unsigned pack = (unsigned)f2bf(hstA) | ((unsigned)f2bf(hstB) << 16);
            *(unsigned*)&nxt[(size_t)(b0 + er2) * HD + j0 + ec2] = pack;
        }
        // PER-WAVE drain + publish: no barrier2. Wave u's flag asserts only
        // its own rows 4u..4u+3 -- which is exactly what it stored.
        asm volatile("s_waitcnt vmcnt(0)" ::: "memory");
        if (lane < 32)
            l2_atomic_swap_nr(mbX + (lane * 4 + pw) * MBW2 + pi * 4 + wave, (unsigned)(t + 2));

        // decode h_t -> out[t-1]: fully post-publish, reads rc(t) which is
        // not overwritten until step t+2 (transitively guarded).
        if (tid < 32 && t > 0) {
            int dr = 2 * rg + (tid >> 4), col = tid & 15;
            float o = decb_r;
            #pragma unroll
            for (int kq = 0; kq < 4; ++kq)
                o += rc[((kq * 5 + 4) * 16 + dr) * RCP + col];
            size_t oi = (size_t)(t - 1) * (BS * NO) + (size_t)(b0 + dr) * NO + 16 * dt + col;
            if (isf32) ((float*)outv)[oi] = o; else ((u16*)outv)[oi] = f2bf(o);
        }
    }

    // ---- epilogue: out[511] = decode(h_512); final hidden ----
    {
        {   // per-wave poll for h_512 (value TS+1)
            const unsigned target = (unsigned)(TS + 1);
            for (;;) {
                unsigned v = target;
                if (lane < 32) v = l2_atomic_add(mbW + lane, 0u);
                if (__all((int)(v >= target))) break;
            }
        }
        float* rc = redC[0];         // TS even -> free buffer parity
        bf16x8 a[8];
        load_a_frags(h0buf + (size_t)(b0 + m) * HD + wave * 256 + quad * 8, a);
        f32x4 ac = (f32x4){0.f, 0.f, 0.f, 0.f};
        #pragma unroll
        for (int ks = 0; ks < 8; ++ks)
            ac = __builtin_amdgcn_mfma_f32_16x16x32_bf16(a[ks], dfr[ks], ac, 0, 0, 0);
        #pragma unroll
        for (int r = 0; r < 4; ++r)
            rc[((wave * 5 + 4) * 16 + quad * 4 + r) * RCP + m] = ac[r];
        __syncthreads();
        if (tid < 32) {
            int dr = 2 * rg + (tid >> 4), col = tid & 15;
            float o = decb_r;
            #pragma unroll
            for (int kq = 0; kq < 4; ++kq)
                o += rc[((kq * 5 + 4) * 16 + dr) * RCP + col];
            size_t oi = (size_t)511 * (BS * NO) + (size_t)(b0 + dr) * NO + 16 * dt + col;
            if (isf32) ((float*)outv)[oi] = o; else ((u16*)outv)[oi] = f2bf(o);
        }
    }
    {   // final hidden straight from registers (paired columns)
        size_t oi = (size_t)TS * BS * NO + (size_t)(b0 + er2) * HD + j0 + ec2;
        if (isf32) { ((float*)outv)[oi] = hstA; ((float*)outv)[oi + 1] = hstB; }
        else {
            unsigned pack = (unsigned)f2bf(hstA) | ((unsigned)f2bf(hstB) << 16);
            *(unsigned*)&((u16*)outv)[oi] = pack;
        }
    }
}

extern "C" void kernel_launch(void* const* d_in, const int* in_sizes, int n_in,
                              void* d_out, int out_size, void* d_ws, size_t ws_size,
                              hipStream_t stream) {
    (void)in_sizes; (void)n_in; (void)out_size; (void)ws_size;
    const void* xv       = d_in[0];
    const void* encwv    = d_in[1];
    const void* encbv    = d_in[2];
    const void* recwv    = d_in[3];
    const void* fgtwv    = d_in[4];
    const void* decwv    = d_in[5];
    const void* decbv    = d_in[6];
    const void* hinitwv  = d_in[7];
    const void* hinitbv  = d_in[8];
    void* outv = d_out;

    unsigned* tickets = (unsigned*)d_ws;                       // 8 x 64B-stride
    unsigned* mboxes  = (unsigned*)((char*)d_ws + 4096);       // 8 x 32 x 4 x 128B = 128KB
    u16* h0buf = (u16*)((char*)d_ws + 524288);
    u16* h1buf = h0buf + (size_t)BS * HD;

    // zero tickets + mailboxes each launch (ws is re-poisoned to 0xAA)
    hipMemsetAsync(d_ws, 0, 4096 + 8 * 32 * 4 * MBW2 * 4, stream);

    void* args[] = { (void*)&xv, (void*)&encwv, (void*)&encbv, (void*)&recwv,
                     (void*)&fgtwv, (void*)&decwv, (void*)&decbv,
                     (void*)&hinitwv, (void*)&hinitbv,
                     (void*)&outv, (void*)&h0buf, (void*)&h1buf,
                     (void*)&tickets, (void*)&mboxes };
    // NEVER ignore the cooperative-launch return code.
    hipError_t err = hipLaunchCooperativeKernel((void*)arnn_xcd, dim3(NWG), dim3(NT), args, 0, stream);
    if (err != hipSuccess) {
        hipLaunchKernelGGL(arnn_xcd, dim3(NWG), dim3(NT), 0, stream,
                           xv, encwv, encbv, recwv, fgtwv, decwv, decbv,
                           hinitwv, hinitbv, outv, h0buf, h1buf, tickets, mboxes);
    }
}